// Round 6
// baseline (212.427 us; speedup 1.0000x reference)
//
#include <hip/hip_runtime.h>
#include <cstdint>
#include <cstddef>

// B=4, S=2048, D=1024, H=16, HD=64 ; BS=8192 rows; qkv N=3072
typedef float  f32x4  __attribute__((ext_vector_type(4)));
typedef __bf16 bf16x8 __attribute__((ext_vector_type(8)));
typedef __bf16 bf16x4 __attribute__((ext_vector_type(4)));

#define DEVI static __device__ __forceinline__

DEVI f32x4 mfma_bf16(bf16x8 a, bf16x8 b, f32x4 c) {
  return __builtin_amdgcn_mfma_f32_16x16x32_bf16(a, b, c, 0, 0, 0);
}

DEVI void gload_lds16(const void* g, void* l) {
  __builtin_amdgcn_global_load_lds(
      (const __attribute__((address_space(1))) void*)g,
      (__attribute__((address_space(3))) void*)l, 16, 0, 0);
}

// ---------------- cast f32 -> bf16, 4 elems/thread ----------------
__global__ void k_cast_bf16(const float* __restrict__ src, __bf16* __restrict__ dst, int n4) {
  int i = blockIdx.x * blockDim.x + threadIdx.x;
  if (i < n4) {
    float4 v = reinterpret_cast<const float4*>(src)[i];
    bf16x4 r;
    r.x = (__bf16)v.x; r.y = (__bf16)v.y; r.z = (__bf16)v.z; r.w = (__bf16)v.w;
    reinterpret_cast<bf16x4*>(dst)[i] = r;
  }
}

// ---------------- transpose + cast: f32 [R][C] -> bf16 [C][R] ----------------
__global__ void k_transpose_cast(const float* __restrict__ src, __bf16* __restrict__ dst,
                                 int R, int C) {
  __shared__ __bf16 tile[64][65];
  const int tx = threadIdx.x & 63, ty = threadIdx.x >> 6;
  const int r0 = blockIdx.y * 64, c0 = blockIdx.x * 64;
#pragma unroll
  for (int i = 0; i < 16; ++i) {
    int r = ty * 16 + i;
    tile[r][tx] = (__bf16)src[(size_t)(r0 + r) * C + c0 + tx];
  }
  __syncthreads();
#pragma unroll
  for (int i = 0; i < 16; ++i) {
    int c = ty * 16 + i;
    dst[(size_t)(c0 + c) * R + r0 + tx] = tile[tx][c];
  }
}

// ---------------- transpose V section of qkv -> VT [B*H][64][2048] ----------------
__global__ void k_transpose_v(const __bf16* __restrict__ qkv, __bf16* __restrict__ VT) {
  __shared__ __bf16 tile[64][65];
  const int tx = threadIdx.x & 63, ty = threadIdx.x >> 6;
  const int bh = blockIdx.y;              // 0..63
  const int b = bh >> 4, h = bh & 15;
  const int s0 = blockIdx.x * 64;
  const __bf16* src = qkv + (size_t)(b * 2048) * 3072 + 2048 + h * 64;
#pragma unroll
  for (int i = 0; i < 16; ++i) {
    int s = ty * 16 + i;
    tile[s][tx] = src[(size_t)(s0 + s) * 3072 + tx];
  }
  __syncthreads();
  __bf16* dst = VT + (size_t)bh * 64 * 2048;
#pragma unroll
  for (int i = 0; i < 16; ++i) {
    int d = ty * 16 + i;
    dst[(size_t)d * 2048 + s0 + tx] = tile[tx][d];
  }
}

// ---------------- bf16 GEMM, 256x256 tile, 4-phase/K-tile deep pipeline ----------------
// C[M][N] = A[M][K] * Bt[N][K]^T + bias. BM=BN=256, BK=64 as two kk-halves of 32.
// 512 threads = 8 waves (wr=w>>2 over M, wc=w&3 over N); per-wave 128x64 out, acc[8][4].
// LDS: [2 buf][2 kk] 16KB slots for A and B (128KB). Supertile layout (16 rows x 64B,
// column-slot-major within 1KB) -> conflict-free gload_lds writes AND ds_read_b128 reads.
// Each phase: {ds_read frags; stage 1 half-tile of t+1; s_barrier; lgkmcnt(0);
// setprio(1); 16 MFMA; setprio(0); s_barrier}. Counted vmcnt(4) at phases 2 & 4 only.
template <int MODE>  // 0: bf16 out, 1: f32 out
__global__ __launch_bounds__(512, 2) void k_gemm8(
    const __bf16* __restrict__ A, const __bf16* __restrict__ Bt,
    const float* __restrict__ bias, void* __restrict__ Cv,
    int M, int N, int K, int nbx) {
  __shared__ alignas(16) __bf16 Asl[2][2][256 * 32];  // 64 KB
  __shared__ alignas(16) __bf16 Bsl[2][2][256 * 32];  // 64 KB
  const int t = threadIdx.x;
  const int w = t >> 6, lane = t & 63;
  const int l15 = lane & 15, lg = lane >> 4;
  const int wr = w >> 2, wc = w & 3;

  // XCD-aware bijective swizzle (gridDim.x % 8 == 0)
  const int nwg = gridDim.x;
  const int wgid = (blockIdx.x & 7) * (nwg >> 3) + (blockIdx.x >> 3);
  const int m0 = (wgid / nbx) * 256;
  const int n0 = (wgid % nbx) * 256;

  // staging: lane (lrow=lane&15, lcol=lane>>4) loads A[m0+st*16+lrow][kt*64+kk*32+lcol*8 ..+8]
  // into supertile st (st = w*2+i), LDS dest = slot + st*1024 (+ lane*16 by HW).
  const int lrow = lane & 15, lcol = lane >> 4;
  const __bf16* pa = A + (size_t)(m0 + lrow) * K + lcol * 8;
  const __bf16* pb = Bt + (size_t)(n0 + lrow) * K + lcol * 8;

  auto stageA = [&](int buf, int kt, int kk) {
    const __bf16* src = pa + (size_t)kt * 64 + kk * 32;
    char* dst = (char*)&Asl[buf][kk][0];
#pragma unroll
    for (int i = 0; i < 2; ++i) {
      const int st = w * 2 + i;
      gload_lds16(src + (size_t)st * 16 * K, dst + st * 1024);
    }
  };
  auto stageB = [&](int buf, int kt, int kk) {
    const __bf16* src = pb + (size_t)kt * 64 + kk * 32;
    char* dst = (char*)&Bsl[buf][kk][0];
#pragma unroll
    for (int i = 0; i < 2; ++i) {
      const int st = w * 2 + i;
      gload_lds16(src + (size_t)st * 16 * K, dst + st * 1024);
    }
  };

  // frag read offsets within a 16KB [kk] slot: supertile*1024 + lg*256 + l15*16
  const int aoff = wr * 8192 + lg * 256 + l15 * 16;
  const int boff = wc * 4096 + lg * 256 + l15 * 16;

  f32x4 acc[8][4] = {};
  const int nK = K >> 6;

  // prologue: tile 0 fully staged; kk0 landed, kk1 (4 loads) left in flight.
  stageA(0, 0, 0); stageB(0, 0, 0);
  stageA(0, 0, 1); stageB(0, 0, 1);
  asm volatile("s_waitcnt vmcnt(4)" ::: "memory");
  __builtin_amdgcn_s_barrier();

  for (int kt = 0; kt < nK; ++kt) {
    const int buf = kt & 1, nbuf = buf ^ 1;
    const bool pf = (kt + 1) < nK;
    const char* a0 = (const char*)&Asl[buf][0][0];
    const char* b0 = (const char*)&Bsl[buf][0][0];
    const char* a1 = (const char*)&Asl[buf][1][0];
    const char* b1 = (const char*)&Bsl[buf][1][0];
    bf16x8 af[4], bfr[4];

    // ---- phase 1: (m0-3 x n0-3, kk0) ----
#pragma unroll
    for (int m = 0; m < 4; ++m) af[m] = *(const bf16x8*)(a0 + aoff + m * 1024);
#pragma unroll
    for (int n = 0; n < 4; ++n) bfr[n] = *(const bf16x8*)(b0 + boff + n * 1024);
    if (pf) stageA(nbuf, kt + 1, 0);
    __builtin_amdgcn_s_barrier();
    asm volatile("s_waitcnt lgkmcnt(0)" ::: "memory");
    __builtin_amdgcn_s_setprio(1);
#pragma unroll
    for (int m = 0; m < 4; ++m)
#pragma unroll
      for (int n = 0; n < 4; ++n)
        acc[m][n] = mfma_bf16(af[m], bfr[n], acc[m][n]);
    __builtin_amdgcn_s_setprio(0);
    __builtin_amdgcn_s_barrier();

    // ---- phase 2: (m4-7 x n0-3, kk0), reuse bfr ----
#pragma unroll
    for (int m = 0; m < 4; ++m) af[m] = *(const bf16x8*)(a0 + aoff + (m + 4) * 1024);
    if (pf) stageB(nbuf, kt + 1, 0);
    __builtin_amdgcn_s_barrier();
    asm volatile("s_waitcnt lgkmcnt(0)" ::: "memory");
    __builtin_amdgcn_s_setprio(1);
#pragma unroll
    for (int m = 0; m < 4; ++m)
#pragma unroll
      for (int n = 0; n < 4; ++n)
        acc[m + 4][n] = mfma_bf16(af[m], bfr[n], acc[m + 4][n]);
    __builtin_amdgcn_s_setprio(0);
    if (pf) asm volatile("s_waitcnt vmcnt(4)" ::: "memory");  // this tile's kk1 landed
    else    asm volatile("s_waitcnt vmcnt(0)" ::: "memory");
    __builtin_amdgcn_s_barrier();

    // ---- phase 3: (m0-3 x n0-3, kk1) ----
#pragma unroll
    for (int m = 0; m < 4; ++m) af[m] = *(const bf16x8*)(a1 + aoff + m * 1024);
#pragma unroll
    for (int n = 0; n < 4; ++n) bfr[n] = *(const bf16x8*)(b1 + boff + n * 1024);
    if (pf) stageA(nbuf, kt + 1, 1);
    __builtin_amdgcn_s_barrier();
    asm volatile("s_waitcnt lgkmcnt(0)" ::: "memory");
    __builtin_amdgcn_s_setprio(1);
#pragma unroll
    for (int m = 0; m < 4; ++m)
#pragma unroll
      for (int n = 0; n < 4; ++n)
        acc[m][n] = mfma_bf16(af[m], bfr[n], acc[m][n]);
    __builtin_amdgcn_s_setprio(0);
    __builtin_amdgcn_s_barrier();

    // ---- phase 4: (m4-7 x n0-3, kk1) ----
#pragma unroll
    for (int m = 0; m < 4; ++m) af[m] = *(const bf16x8*)(a1 + aoff + (m + 4) * 1024);
    if (pf) stageB(nbuf, kt + 1, 1);
    __builtin_amdgcn_s_barrier();
    asm volatile("s_waitcnt lgkmcnt(0)" ::: "memory");
    __builtin_amdgcn_s_setprio(1);
#pragma unroll
    for (int m = 0; m < 4; ++m)
#pragma unroll
      for (int n = 0; n < 4; ++n)
        acc[m + 4][n] = mfma_bf16(af[m], bfr[n], acc[m + 4][n]);
    __builtin_amdgcn_s_setprio(0);
    if (pf) asm volatile("s_waitcnt vmcnt(4)" ::: "memory");  // next tile's kk0 landed
    __builtin_amdgcn_s_barrier();
  }

#pragma unroll
  for (int n = 0; n < 4; ++n) {
    const int gcol = n0 + wc * 64 + n * 16 + l15;
    const float bv = bias ? bias[gcol] : 0.0f;
#pragma unroll
    for (int m = 0; m < 8; ++m) {
      const int grow = m0 + wr * 128 + m * 16 + (lg << 2);
#pragma unroll
      for (int r = 0; r < 4; ++r) {
        float v = acc[m][n][r] + bv;
        if (MODE == 0)
          ((__bf16*)Cv)[(size_t)(grow + r) * N + gcol] = (__bf16)v;
        else
          ((float*)Cv)[(size_t)(grow + r) * N + gcol] = v;
      }
    }
  }
}

// ---------------- causal flash attention (QBLK=128, 8 waves x 16 q-rows) ----------------
// grid: 1024 blocks; qt = 15-(bid>>6) (heavy-first LPT), bh = bid&63 (per-head XCD affinity).
// KV tile = 64, double-buffered LDS staging (48KB -> 3 blocks/CU = 6 waves/SIMD).
// Swapped QK^T (mfma(K,Q)): full q-row's scores in-lane; exp2-domain softmax; defer-max.
__global__ __launch_bounds__(512, 2) void k_attn(
    const __bf16* __restrict__ qkv,  // [8192][3072]
    const __bf16* __restrict__ VT,   // [B*H][64][2048]
    __bf16* __restrict__ Y) {        // [8192][1024]
  __shared__ __bf16 kbuf[2][64 * 64];  // 8 KB per buf, row=kv pos, 128B rows, XOR-swizzled
  __shared__ __bf16 vbuf[2][64 * 64];  // 8 KB per buf, row=d,      128B rows, XOR-swizzled
  __shared__ __bf16 p_lds[8][1024];    // per-wave 16x64 P tile (row=q, col=kv), XOR swizzled
  const int t = threadIdx.x, w = t >> 6, lane = t & 63;
  const int l15 = lane & 15, lg = lane >> 4;
  const int bid = blockIdx.x;
  const int qt = 15 - (bid >> 6);   // heavy q-blocks first
  const int bh = bid & 63;          // same head -> same XCD (round-robin dispatch)
  const int b = bh >> 4, h = bh & 15;
  const int q0 = qt * 128;
  const int nkv = 2 * qt + 2;
  const float SCL = 0.125f * 1.44269504f;  // scale * log2(e): softmax in exp2 domain

  const size_t qrow = (size_t)(b * 2048 + q0 + w * 16 + l15);
  const bf16x8 qf0 = *(const bf16x8*)(qkv + qrow * 3072 + h * 64 + lg * 8);
  const bf16x8 qf1 = *(const bf16x8*)(qkv + qrow * 3072 + h * 64 + 32 + lg * 8);

  const __bf16* kg = qkv + (size_t)(b * 2048) * 3072 + 1024 + h * 64;  // +kvpos*3072
  const __bf16* vg = VT + (size_t)bh * 64 * 2048;                      // +d*2048

  // 512 threads stage 8KB K + 8KB V per tile: 1 chunk of 16B each.
  const int srow = t >> 3, sslot = t & 7;          // row 0..63, slot 0..7
  const int sb = (sslot ^ (srow & 7)) << 4;        // pre-swizzled source byte
  auto stage = [&](int bi, int kvi) {
    gload_lds16((const char*)(kg + (size_t)(kvi * 64 + srow) * 3072) + sb,
                (char*)kbuf[bi] + w * 1024);
    gload_lds16((const char*)(vg + (size_t)srow * 2048 + kvi * 64) + sb,
                (char*)vbuf[bi] + w * 1024);
  };

  f32x4 o[4] = {};
  float mr = -1e30f, lr = 0.0f;   // running max (scaled domain) & sum for q-row w*16+l15
  __bf16* pl = &p_lds[w][0];

  stage(0, 0);
  asm volatile("s_waitcnt vmcnt(0)" ::: "memory");
  __syncthreads();

  for (int kv = 0; kv < nkv; ++kv) {
    if (kv + 1 < nkv) stage((kv + 1) & 1, kv + 1);  // prefetch next tile
    const char* kb = (const char*)kbuf[kv & 1];
    const char* vb = (const char*)vbuf[kv & 1];

    // QK^T swapped: s[nb] = K_tile * Q -> D[kv_local][q]; lane: q = l15, kv = nb*16+lg*4+r
    f32x4 s[4] = {};
    __builtin_amdgcn_s_setprio(1);
#pragma unroll
    for (int nb = 0; nb < 4; ++nb) {
      int row = nb * 16 + l15;
      int sw = (row & 7) << 4;
      bf16x8 k0 = *(const bf16x8*)(kb + row * 128 + ((lg * 16) ^ sw));
      bf16x8 k1 = *(const bf16x8*)(kb + row * 128 + ((64 + lg * 16) ^ sw));
      s[nb] = mfma_bf16(k0, qf0, s[nb]);
      s[nb] = mfma_bf16(k1, qf1, s[nb]);
    }
    __builtin_amdgcn_s_setprio(0);

    // causal mask: wave-uniform guard (tile reaches past this wave's first q-row)
    if (((kv + 1) << 6) > q0 + w * 16) {
      const int qg = q0 + w * 16 + l15;
#pragma unroll
      for (int nb = 0; nb < 4; ++nb)
#pragma unroll
        for (int r = 0; r < 4; ++r)
          if (kv * 64 + nb * 16 + lg * 4 + r > qg) s[nb][r] = -1e30f;
    }

    // row max: in-lane tree over 16 + xor16/32 (reduce over lg groups)
    float pm = -3e38f;
#pragma unroll
    for (int nb = 0; nb < 4; ++nb)
      pm = fmaxf(pm, fmaxf(fmaxf(s[nb][0], s[nb][1]), fmaxf(s[nb][2], s[nb][3])));
    pm = fmaxf(pm, __shfl_xor(pm, 16));
    pm = fmaxf(pm, __shfl_xor(pm, 32));
    pm *= SCL;

    if (!__all(pm <= mr + 8.0f)) {  // defer-max: rescale only when max grows
      float nm = fmaxf(mr, pm);
      float alpha = __builtin_amdgcn_exp2f(mr - nm);
      lr *= alpha;
      mr = nm;
#pragma unroll
      for (int r = 0; r < 4; ++r) {
        float aO = __shfl(alpha, lg * 4 + r);   // alpha of q-row lg*4+r
        o[0][r] *= aO; o[1][r] *= aO; o[2][r] *= aO; o[3][r] *= aO;
      }
    }

    // p = exp2(s*SCL - mr); sum in-lane + xor16/32
    float ps = 0.0f;
    bf16x4 pk[4];
#pragma unroll
    for (int nb = 0; nb < 4; ++nb) {
      f32x4 pe;
#pragma unroll
      for (int r = 0; r < 4; ++r)
        pe[r] = __builtin_amdgcn_exp2f(fmaf(s[nb][r], SCL, -mr));
      ps += (pe[0] + pe[1]) + (pe[2] + pe[3]);
      pk[nb][0] = (__bf16)pe[0]; pk[nb][1] = (__bf16)pe[1];
      pk[nb][2] = (__bf16)pe[2]; pk[nb][3] = (__bf16)pe[3];
    }
    ps += __shfl_xor(ps, 16);
    ps += __shfl_xor(ps, 32);
    lr += ps;

    // store P^T values to p_lds[q=l15][kv], 4x ds_write_b64 (8B blocks, swizzle-safe)
    {
      const int rowb = l15 * 128;
      const int sw = (l15 & 7) << 4;
#pragma unroll
      for (int nb = 0; nb < 4; ++nb) {
        int cb = (nb * 32 + lg * 8) ^ sw;
        *(bf16x4*)((char*)pl + rowb + cb) = pk[nb];
      }
    }
    asm volatile("s_waitcnt lgkmcnt(0)" ::: "memory");
    bf16x8 pf0, pf1;
    {
      const int rowb = l15 * 128;
      const int sw = (l15 & 7) << 4;
      pf0 = *(const bf16x8*)((const char*)pl + rowb + ((lg << 4) ^ sw));
      pf1 = *(const bf16x8*)((const char*)pl + rowb + ((64 + (lg << 4)) ^ sw));
    }
    __builtin_amdgcn_s_setprio(1);
#pragma unroll
    for (int nb = 0; nb < 4; ++nb) {
      int row = nb * 16 + l15;
      int sw = (row & 7) << 4;
      bf16x8 v0 = *(const bf16x8*)(vb + row * 128 + ((lg * 16) ^ sw));
      bf16x8 v1 = *(const bf16x8*)(vb + row * 128 + ((64 + lg * 16) ^ sw));
      o[nb] = mfma_bf16(pf0, v0, o[nb]);
      o[nb] = mfma_bf16(pf1, v1, o[nb]);
    }
    __builtin_amdgcn_s_setprio(0);
    asm volatile("s_waitcnt vmcnt(0)" ::: "memory");  // next tile fully staged
    __syncthreads();                                  // everyone done with cur buffers
  }

  float lO[4];
#pragma unroll
  for (int r = 0; r < 4; ++r) lO[r] = __shfl(lr, lg * 4 + r);
#pragma unroll
  for (int nb = 0; nb < 4; ++nb)
#pragma unroll
    for (int r = 0; r < 4; ++r) {
      float v = o[nb][r] / lO[r];
      size_t row = (size_t)(b * 2048 + q0 + w * 16 + lg * 4 + r);
      Y[row * 1024 + h * 64 + nb * 16 + l15] = (__bf16)v;
    }
}

extern "C" void kernel_launch(void* const* d_in, const int* in_sizes, int n_in,
                              void* d_out, int out_size, void* d_ws, size_t ws_size,
                              hipStream_t stream) {
  const float* x      = (const float*)d_in[0];
  const float* w_qkv  = (const float*)d_in[1];
  const float* b_qkv  = (const float*)d_in[2];
  const float* w_proj = (const float*)d_in[3];
  const float* b_proj = (const float*)d_in[4];
  float* out = (float*)d_out;

  char* ws = (char*)d_ws;
  const size_t MB = 1024 * 1024;
  __bf16* xb     = (__bf16*)(ws);            // 16 MiB  [8192][1024]
  __bf16* wqkvT  = (__bf16*)(ws + 16 * MB);  // 6 MiB   [3072][1024]
  __bf16* wprojT = (__bf16*)(ws + 22 * MB);  // 2 MiB   [1024][1024]
  __bf16* qkv    = (__bf16*)(ws + 24 * MB);  // 48 MiB  [8192][3072]
  __bf16* VT     = (__bf16*)(ws + 72 * MB);  // 16 MiB  [64][64][2048]
  __bf16* Y      = (__bf16*)(ws + 88 * MB);  // 16 MiB  [8192][1024]  (ends 104 MiB)

  k_cast_bf16<<<8192, 256, 0, stream>>>(x, xb, 8192 * 1024 / 4);
  k_transpose_cast<<<dim3(48, 16), 256, 0, stream>>>(w_qkv, wqkvT, 1024, 3072);
  k_transpose_cast<<<dim3(16, 16), 256, 0, stream>>>(w_proj, wprojT, 1024, 1024);
  k_gemm8<0><<<dim3(384), 512, 0, stream>>>(xb, wqkvT, b_qkv, qkv, 8192, 3072, 1024, 12);
  k_transpose_v<<<dim3(32, 64), 256, 0, stream>>>(qkv, VT);
  k_attn<<<dim3(1024), 512, 0, stream>>>(qkv, VT, Y);
  k_gemm8<1><<<dim3(128), 512, 0, stream>>>(Y, wprojT, b_proj, out, 8192, 1024, 1024, 4);
}

// Round 7
// 173.823 us; speedup vs baseline: 1.2221x; 1.2221x over previous
//
#include <hip/hip_runtime.h>
#include <cstdint>
#include <cstddef>

// B=4, S=2048, D=1024, H=16, HD=64 ; BS=8192 rows; qkv N=3072
typedef float  f32x4  __attribute__((ext_vector_type(4)));
typedef __bf16 bf16x8 __attribute__((ext_vector_type(8)));
typedef __bf16 bf16x4 __attribute__((ext_vector_type(4)));

#define DEVI static __device__ __forceinline__

DEVI f32x4 mfma_bf16(bf16x8 a, bf16x8 b, f32x4 c) {
  return __builtin_amdgcn_mfma_f32_16x16x32_bf16(a, b, c, 0, 0, 0);
}

DEVI void gload_lds16(const void* g, void* l) {
  __builtin_amdgcn_global_load_lds(
      (const __attribute__((address_space(1))) void*)g,
      (__attribute__((address_space(3))) void*)l, 16, 0, 0);
}

// ---------------- cast f32 -> bf16, 4 elems/thread ----------------
__global__ void k_cast_bf16(const float* __restrict__ src, __bf16* __restrict__ dst, int n4) {
  int i = blockIdx.x * blockDim.x + threadIdx.x;
  if (i < n4) {
    float4 v = reinterpret_cast<const float4*>(src)[i];
    bf16x4 r;
    r.x = (__bf16)v.x; r.y = (__bf16)v.y; r.z = (__bf16)v.z; r.w = (__bf16)v.w;
    reinterpret_cast<bf16x4*>(dst)[i] = r;
  }
}

// ---------------- transpose + cast: f32 [R][C] -> bf16 [C][R] ----------------
__global__ void k_transpose_cast(const float* __restrict__ src, __bf16* __restrict__ dst,
                                 int R, int C) {
  __shared__ __bf16 tile[64][65];
  const int tx = threadIdx.x & 63, ty = threadIdx.x >> 6;
  const int r0 = blockIdx.y * 64, c0 = blockIdx.x * 64;
#pragma unroll
  for (int i = 0; i < 16; ++i) {
    int r = ty * 16 + i;
    tile[r][tx] = (__bf16)src[(size_t)(r0 + r) * C + c0 + tx];
  }
  __syncthreads();
#pragma unroll
  for (int i = 0; i < 16; ++i) {
    int c = ty * 16 + i;
    dst[(size_t)(c0 + c) * R + r0 + tx] = tile[tx][c];
  }
}

// ---------------- bf16 GEMM: C[M][N] = A[M][K] * Bt[N][K]^T + bias ----------------
// 128x128 tile, BK=64, 4 waves (2x2), global_load_lds staging with both-sides XOR swizzle.
// MODE 0: bf16 out; for V-section blocks (n0>=2048, VT!=null) writes transposed into
// VT[bh][d][s] with packed bf16x4 stores (fuses the V transpose into the epilogue).
// MODE 1: f32 out.
template <int MODE>
__global__ __launch_bounds__(256, 2) void k_gemm_bt(
    const __bf16* __restrict__ A, const __bf16* __restrict__ Bt,
    const float* __restrict__ bias, void* __restrict__ Cv,
    __bf16* __restrict__ VT,
    int M, int N, int K, int nbx) {
  __shared__ __bf16 As[128 * 64];
  __shared__ __bf16 Bs[128 * 64];
  const int t = threadIdx.x;
  const int w = t >> 6, lane = t & 63;
  const int l15 = lane & 15, lg = lane >> 4;
  const int m0 = (blockIdx.x / nbx) * 128;
  const int n0 = (blockIdx.x % nbx) * 128;
  const int wr = w >> 1, wc = w & 1;
  const int lrow = lane >> 3, lslot = lane & 7;

  f32x4 acc[4][4] = {};

  const int nK = K >> 6;
  for (int kt = 0; kt < nK; ++kt) {
    const __bf16* Ab = A + (size_t)m0 * K + kt * 64;
    const __bf16* Bb = Bt + (size_t)n0 * K + kt * 64;
#pragma unroll
    for (int c = 0; c < 4; ++c) {
      int seg = w * 4 + c;            // 16 segments of 1KB per tile
      int row = seg * 8 + lrow;       // 0..127
      int cb = (lslot ^ (row & 7)) << 4;  // pre-swizzled global source byte
      gload_lds16((const char*)(Ab + (size_t)row * K) + cb, (char*)As + seg * 1024);
      gload_lds16((const char*)(Bb + (size_t)row * K) + cb, (char*)Bs + seg * 1024);
    }
    __syncthreads();
#pragma unroll
    for (int ks = 0; ks < 2; ++ks) {
      bf16x8 af[4], bfr[4];
      const int cb = ks * 64 + (lg << 4);
#pragma unroll
      for (int m = 0; m < 4; ++m) {
        int row = wr * 64 + m * 16 + l15;
        af[m] = *(const bf16x8*)((const char*)As + row * 128 + (cb ^ ((row & 7) << 4)));
      }
#pragma unroll
      for (int n = 0; n < 4; ++n) {
        int row = wc * 64 + n * 16 + l15;
        bfr[n] = *(const bf16x8*)((const char*)Bs + row * 128 + (cb ^ ((row & 7) << 4)));
      }
#pragma unroll
      for (int m = 0; m < 4; ++m)
#pragma unroll
        for (int n = 0; n < 4; ++n)
          acc[m][n] = mfma_bf16(af[m], bfr[n], acc[m][n]);
    }
    __syncthreads();
  }

  const bool vsec = (MODE == 0) && (VT != nullptr) && (n0 >= 2048);
#pragma unroll
  for (int n = 0; n < 4; ++n) {
    const int gcol = n0 + wc * 64 + n * 16 + l15;
    const float bv = bias ? bias[gcol] : 0.0f;
#pragma unroll
    for (int m = 0; m < 4; ++m) {
      const int grow = m0 + wr * 64 + m * 16 + (lg << 2);
      if (vsec) {
        // V section: write VT[(b*16+h)*64 + d][s], 4 consecutive s -> packed store
        const int hd = gcol - 2048;           // h*64 + d
        const int b = grow >> 11, s0v = grow & 2047;
        bf16x4 pk;
#pragma unroll
        for (int r = 0; r < 4; ++r) pk[r] = (__bf16)(acc[m][n][r] + bv);
        *(bf16x4*)(VT + ((size_t)(b * 16) * 64 + hd) * 2048 + s0v) = pk;
      } else {
#pragma unroll
        for (int r = 0; r < 4; ++r) {
          float v = acc[m][n][r] + bv;
          if (MODE == 0)
            ((__bf16*)Cv)[(size_t)(grow + r) * N + gcol] = (__bf16)v;
          else
            ((float*)Cv)[(size_t)(grow + r) * N + gcol] = v;
        }
      }
    }
  }
}

// ---------------- causal flash attention (QBLK=128, 8 waves x 16 q-rows) ----------------
// grid: 1024 blocks; qt = 15-(bid>>6) (heavy-first LPT), bh = bid&63 (per-head XCD affinity).
// KV tile = 64, double-buffered LDS staging (48KB -> 3 blocks/CU = 6 waves/SIMD).
// Swapped QK^T (mfma(K,Q)): full q-row's scores in-lane; exp2-domain softmax; defer-max.
__global__ __launch_bounds__(512, 2) void k_attn(
    const __bf16* __restrict__ qkv,  // [8192][3072]
    const __bf16* __restrict__ VT,   // [B*H][64][2048]
    __bf16* __restrict__ Y) {        // [8192][1024]
  __shared__ __bf16 kbuf[2][64 * 64];  // 8 KB per buf, row=kv pos, 128B rows, XOR-swizzled
  __shared__ __bf16 vbuf[2][64 * 64];  // 8 KB per buf, row=d,      128B rows, XOR-swizzled
  __shared__ __bf16 p_lds[8][1024];    // per-wave 16x64 P tile (row=q, col=kv), XOR swizzled
  const int t = threadIdx.x, w = t >> 6, lane = t & 63;
  const int l15 = lane & 15, lg = lane >> 4;
  const int bid = blockIdx.x;
  const int qt = 15 - (bid >> 6);   // heavy q-blocks first
  const int bh = bid & 63;          // same head -> same XCD (round-robin dispatch)
  const int b = bh >> 4, h = bh & 15;
  const int q0 = qt * 128;
  const int nkv = 2 * qt + 2;
  const float SCL = 0.125f * 1.44269504f;  // scale * log2(e): softmax in exp2 domain

  const size_t qrow = (size_t)(b * 2048 + q0 + w * 16 + l15);
  const bf16x8 qf0 = *(const bf16x8*)(qkv + qrow * 3072 + h * 64 + lg * 8);
  const bf16x8 qf1 = *(const bf16x8*)(qkv + qrow * 3072 + h * 64 + 32 + lg * 8);

  const __bf16* kg = qkv + (size_t)(b * 2048) * 3072 + 1024 + h * 64;  // +kvpos*3072
  const __bf16* vg = VT + (size_t)bh * 64 * 2048;                      // +d*2048

  // 512 threads stage 8KB K + 8KB V per tile: 1 chunk of 16B each.
  const int srow = t >> 3, sslot = t & 7;          // row 0..63, slot 0..7
  const int sb = (sslot ^ (srow & 7)) << 4;        // pre-swizzled source byte
  auto stage = [&](int bi, int kvi) {
    gload_lds16((const char*)(kg + (size_t)(kvi * 64 + srow) * 3072) + sb,
                (char*)kbuf[bi] + w * 1024);
    gload_lds16((const char*)(vg + (size_t)srow * 2048 + kvi * 64) + sb,
                (char*)vbuf[bi] + w * 1024);
  };

  f32x4 o[4] = {};
  float mr = -1e30f, lr = 0.0f;   // running max (scaled domain) & sum for q-row w*16+l15
  __bf16* pl = &p_lds[w][0];

  stage(0, 0);
  asm volatile("s_waitcnt vmcnt(0)" ::: "memory");
  __syncthreads();

  for (int kv = 0; kv < nkv; ++kv) {
    if (kv + 1 < nkv) stage((kv + 1) & 1, kv + 1);  // prefetch next tile
    const char* kb = (const char*)kbuf[kv & 1];
    const char* vb = (const char*)vbuf[kv & 1];

    // QK^T swapped: s[nb] = K_tile * Q -> D[kv_local][q]; lane: q = l15, kv = nb*16+lg*4+r
    f32x4 s[4] = {};
    __builtin_amdgcn_s_setprio(1);
#pragma unroll
    for (int nb = 0; nb < 4; ++nb) {
      int row = nb * 16 + l15;
      int sw = (row & 7) << 4;
      bf16x8 k0 = *(const bf16x8*)(kb + row * 128 + ((lg * 16) ^ sw));
      bf16x8 k1 = *(const bf16x8*)(kb + row * 128 + ((64 + lg * 16) ^ sw));
      s[nb] = mfma_bf16(k0, qf0, s[nb]);
      s[nb] = mfma_bf16(k1, qf1, s[nb]);
    }
    __builtin_amdgcn_s_setprio(0);

    // causal mask: wave-uniform guard (tile reaches past this wave's first q-row)
    if (((kv + 1) << 6) > q0 + w * 16) {
      const int qg = q0 + w * 16 + l15;
#pragma unroll
      for (int nb = 0; nb < 4; ++nb)
#pragma unroll
        for (int r = 0; r < 4; ++r)
          if (kv * 64 + nb * 16 + lg * 4 + r > qg) s[nb][r] = -1e30f;
    }

    // row max: in-lane tree over 16 + xor16/32 (reduce over lg groups)
    float pm = -3e38f;
#pragma unroll
    for (int nb = 0; nb < 4; ++nb)
      pm = fmaxf(pm, fmaxf(fmaxf(s[nb][0], s[nb][1]), fmaxf(s[nb][2], s[nb][3])));
    pm = fmaxf(pm, __shfl_xor(pm, 16));
    pm = fmaxf(pm, __shfl_xor(pm, 32));
    pm *= SCL;

    if (!__all(pm <= mr + 8.0f)) {  // defer-max: rescale only when max grows
      float nm = fmaxf(mr, pm);
      float alpha = __builtin_amdgcn_exp2f(mr - nm);
      lr *= alpha;
      mr = nm;
#pragma unroll
      for (int r = 0; r < 4; ++r) {
        float aO = __shfl(alpha, lg * 4 + r);   // alpha of q-row lg*4+r
        o[0][r] *= aO; o[1][r] *= aO; o[2][r] *= aO; o[3][r] *= aO;
      }
    }

    // p = exp2(s*SCL - mr); sum in-lane + xor16/32
    float ps = 0.0f;
    bf16x4 pk[4];
#pragma unroll
    for (int nb = 0; nb < 4; ++nb) {
      f32x4 pe;
#pragma unroll
      for (int r = 0; r < 4; ++r)
        pe[r] = __builtin_amdgcn_exp2f(fmaf(s[nb][r], SCL, -mr));
      ps += (pe[0] + pe[1]) + (pe[2] + pe[3]);
      pk[nb][0] = (__bf16)pe[0]; pk[nb][1] = (__bf16)pe[1];
      pk[nb][2] = (__bf16)pe[2]; pk[nb][3] = (__bf16)pe[3];
    }
    ps += __shfl_xor(ps, 16);
    ps += __shfl_xor(ps, 32);
    lr += ps;

    // store P^T values to p_lds[q=l15][kv], 4x ds_write_b64 (8B blocks, swizzle-safe)
    {
      const int rowb = l15 * 128;
      const int sw = (l15 & 7) << 4;
#pragma unroll
      for (int nb = 0; nb < 4; ++nb) {
        int cb = (nb * 32 + lg * 8) ^ sw;
        *(bf16x4*)((char*)pl + rowb + cb) = pk[nb];
      }
    }
    asm volatile("s_waitcnt lgkmcnt(0)" ::: "memory");
    bf16x8 pf0, pf1;
    {
      const int rowb = l15 * 128;
      const int sw = (l15 & 7) << 4;
      pf0 = *(const bf16x8*)((const char*)pl + rowb + ((lg << 4) ^ sw));
      pf1 = *(const bf16x8*)((const char*)pl + rowb + ((64 + (lg << 4)) ^ sw));
    }
    __builtin_amdgcn_s_setprio(1);
#pragma unroll
    for (int nb = 0; nb < 4; ++nb) {
      int row = nb * 16 + l15;
      int sw = (row & 7) << 4;
      bf16x8 v0 = *(const bf16x8*)(vb + row * 128 + ((lg * 16) ^ sw));
      bf16x8 v1 = *(const bf16x8*)(vb + row * 128 + ((64 + lg * 16) ^ sw));
      o[nb] = mfma_bf16(pf0, v0, o[nb]);
      o[nb] = mfma_bf16(pf1, v1, o[nb]);
    }
    __builtin_amdgcn_s_setprio(0);
    asm volatile("s_waitcnt vmcnt(0)" ::: "memory");  // next tile fully staged
    __syncthreads();                                  // everyone done with cur buffers
  }

  float lO[4];
#pragma unroll
  for (int r = 0; r < 4; ++r) lO[r] = __shfl(lr, lg * 4 + r);
#pragma unroll
  for (int nb = 0; nb < 4; ++nb)
#pragma unroll
    for (int r = 0; r < 4; ++r) {
      float v = o[nb][r] / lO[r];
      size_t row = (size_t)(b * 2048 + q0 + w * 16 + lg * 4 + r);
      Y[row * 1024 + h * 64 + nb * 16 + l15] = (__bf16)v;
    }
}

extern "C" void kernel_launch(void* const* d_in, const int* in_sizes, int n_in,
                              void* d_out, int out_size, void* d_ws, size_t ws_size,
                              hipStream_t stream) {
  const float* x      = (const float*)d_in[0];
  const float* w_qkv  = (const float*)d_in[1];
  const float* b_qkv  = (const float*)d_in[2];
  const float* w_proj = (const float*)d_in[3];
  const float* b_proj = (const float*)d_in[4];
  float* out = (float*)d_out;

  char* ws = (char*)d_ws;
  const size_t MB = 1024 * 1024;
  __bf16* xb     = (__bf16*)(ws);            // 16 MiB  [8192][1024]
  __bf16* wqkvT  = (__bf16*)(ws + 16 * MB);  // 6 MiB   [3072][1024]
  __bf16* wprojT = (__bf16*)(ws + 22 * MB);  // 2 MiB   [1024][1024]
  __bf16* qkv    = (__bf16*)(ws + 24 * MB);  // 48 MiB  [8192][3072] (V section unused)
  __bf16* VT     = (__bf16*)(ws + 72 * MB);  // 16 MiB  [64][64][2048]
  __bf16* Y      = (__bf16*)(ws + 88 * MB);  // 16 MiB  [8192][1024]  (ends 104 MiB)

  k_cast_bf16<<<8192, 256, 0, stream>>>(x, xb, 8192 * 1024 / 4);
  k_transpose_cast<<<dim3(48, 16), 256, 0, stream>>>(w_qkv, wqkvT, 1024, 3072);
  k_transpose_cast<<<dim3(16, 16), 256, 0, stream>>>(w_proj, wprojT, 1024, 1024);
  k_gemm_bt<0><<<dim3(64 * 24), 256, 0, stream>>>(xb, wqkvT, b_qkv, qkv, VT, 8192, 3072, 1024, 24);
  k_attn<<<dim3(1024), 512, 0, stream>>>(qkv, VT, Y);
  k_gemm_bt<1><<<dim3(64 * 8), 256, 0, stream>>>(Y, wprojT, b_proj, out, nullptr, 8192, 1024, 1024, 8);
}

// Round 8
// 171.223 us; speedup vs baseline: 1.2406x; 1.0152x over previous
//
#include <hip/hip_runtime.h>
#include <cstdint>
#include <cstddef>

// B=4, S=2048, D=1024, H=16, HD=64 ; BS=8192 rows; qkv N=3072
typedef float  f32x4  __attribute__((ext_vector_type(4)));
typedef __bf16 bf16x8 __attribute__((ext_vector_type(8)));
typedef __bf16 bf16x4 __attribute__((ext_vector_type(4)));

#define DEVI static __device__ __forceinline__

DEVI f32x4 mfma_bf16(bf16x8 a, bf16x8 b, f32x4 c) {
  return __builtin_amdgcn_mfma_f32_16x16x32_bf16(a, b, c, 0, 0, 0);
}

DEVI void gload_lds16(const void* g, void* l) {
  __builtin_amdgcn_global_load_lds(
      (const __attribute__((address_space(1))) void*)g,
      (__attribute__((address_space(3))) void*)l, 16, 0, 0);
}

// ---------------- cast f32 -> bf16, 4 elems/thread ----------------
__global__ void k_cast_bf16(const float* __restrict__ src, __bf16* __restrict__ dst, int n4) {
  int i = blockIdx.x * blockDim.x + threadIdx.x;
  if (i < n4) {
    float4 v = reinterpret_cast<const float4*>(src)[i];
    bf16x4 r;
    r.x = (__bf16)v.x; r.y = (__bf16)v.y; r.z = (__bf16)v.z; r.w = (__bf16)v.w;
    reinterpret_cast<bf16x4*>(dst)[i] = r;
  }
}

// ---------------- transpose + cast: f32 [R][C] -> bf16 [C][R] ----------------
__global__ void k_transpose_cast(const float* __restrict__ src, __bf16* __restrict__ dst,
                                 int R, int C) {
  __shared__ __bf16 tile[64][65];
  const int tx = threadIdx.x & 63, ty = threadIdx.x >> 6;
  const int r0 = blockIdx.y * 64, c0 = blockIdx.x * 64;
#pragma unroll
  for (int i = 0; i < 16; ++i) {
    int r = ty * 16 + i;
    tile[r][tx] = (__bf16)src[(size_t)(r0 + r) * C + c0 + tx];
  }
  __syncthreads();
#pragma unroll
  for (int i = 0; i < 16; ++i) {
    int c = ty * 16 + i;
    dst[(size_t)(c0 + c) * R + r0 + tx] = tile[tx][c];
  }
}

// ---------------- bf16 GEMM: C[M][N] = A[M][K] * Bt[N][K]^T + bias ----------------
// 128x128 tile, BK=64, 4 waves (2x2), global_load_lds staging with both-sides XOR swizzle.
// MODE 0: bf16 out; V-section blocks (n0>=2048, VT!=null) write transposed into
// VT[bh][d][s] with packed bf16x4 stores AND a per-64-tile nibble permutation of s
// (pi^-1) so attention's PV can consume P directly from registers (see k_attn).
// MODE 1: f32 out.
template <int MODE>
__global__ __launch_bounds__(256, 2) void k_gemm_bt(
    const __bf16* __restrict__ A, const __bf16* __restrict__ Bt,
    const float* __restrict__ bias, void* __restrict__ Cv,
    __bf16* __restrict__ VT,
    int M, int N, int K, int nbx) {
  __shared__ __bf16 As[128 * 64];
  __shared__ __bf16 Bs[128 * 64];
  const int t = threadIdx.x;
  const int w = t >> 6, lane = t & 63;
  const int l15 = lane & 15, lg = lane >> 4;
  const int m0 = (blockIdx.x / nbx) * 128;
  const int n0 = (blockIdx.x % nbx) * 128;
  const int wr = w >> 1, wc = w & 1;
  const int lrow = lane >> 3, lslot = lane & 7;

  f32x4 acc[4][4] = {};

  const int nK = K >> 6;
  for (int kt = 0; kt < nK; ++kt) {
    const __bf16* Ab = A + (size_t)m0 * K + kt * 64;
    const __bf16* Bb = Bt + (size_t)n0 * K + kt * 64;
#pragma unroll
    for (int c = 0; c < 4; ++c) {
      int seg = w * 4 + c;            // 16 segments of 1KB per tile
      int row = seg * 8 + lrow;       // 0..127
      int cb = (lslot ^ (row & 7)) << 4;  // pre-swizzled global source byte
      gload_lds16((const char*)(Ab + (size_t)row * K) + cb, (char*)As + seg * 1024);
      gload_lds16((const char*)(Bb + (size_t)row * K) + cb, (char*)Bs + seg * 1024);
    }
    __syncthreads();
#pragma unroll
    for (int ks = 0; ks < 2; ++ks) {
      bf16x8 af[4], bfr[4];
      const int cb = ks * 64 + (lg << 4);
#pragma unroll
      for (int m = 0; m < 4; ++m) {
        int row = wr * 64 + m * 16 + l15;
        af[m] = *(const bf16x8*)((const char*)As + row * 128 + (cb ^ ((row & 7) << 4)));
      }
#pragma unroll
      for (int n = 0; n < 4; ++n) {
        int row = wc * 64 + n * 16 + l15;
        bfr[n] = *(const bf16x8*)((const char*)Bs + row * 128 + (cb ^ ((row & 7) << 4)));
      }
#pragma unroll
      for (int m = 0; m < 4; ++m)
#pragma unroll
        for (int n = 0; n < 4; ++n)
          acc[m][n] = mfma_bf16(af[m], bfr[n], acc[m][n]);
    }
    __syncthreads();
  }

  const bool vsec = (MODE == 0) && (VT != nullptr) && (n0 >= 2048);
#pragma unroll
  for (int n = 0; n < 4; ++n) {
    const int gcol = n0 + wc * 64 + n * 16 + l15;
    const float bv = bias ? bias[gcol] : 0.0f;
#pragma unroll
    for (int m = 0; m < 4; ++m) {
      const int grow = m0 + wr * 64 + m * 16 + (lg << 2);
      if (vsec) {
        // V section: write VT[(b*16+h)*64 + d][s'] where s' applies the per-64-tile
        // nibble permutation pi^-1: m<4:2m ; 4..7:2m-7 ; 8..11:2m-8 ; 12..15:2m-15.
        const int hd = gcol - 2048;           // h*64 + d
        const int b = grow >> 11, s0v = grow & 2047;
        const int nib = (s0v >> 2) & 15;
        const int nib2 = (nib < 4) ? 2 * nib : (nib < 8) ? 2 * nib - 7
                        : (nib < 12) ? 2 * nib - 8 : 2 * nib - 15;
        const int sp = (s0v & ~63) | (nib2 << 2);
        bf16x4 pkv;
#pragma unroll
        for (int r = 0; r < 4; ++r) pkv[r] = (__bf16)(acc[m][n][r] + bv);
        *(bf16x4*)(VT + ((size_t)(b * 16) * 64 + hd) * 2048 + sp) = pkv;
      } else {
#pragma unroll
        for (int r = 0; r < 4; ++r) {
          float v = acc[m][n][r] + bv;
          if (MODE == 0)
            ((__bf16*)Cv)[(size_t)(grow + r) * N + gcol] = (__bf16)v;
          else
            ((float*)Cv)[(size_t)(grow + r) * N + gcol] = v;
        }
      }
    }
  }
}

// ---------------- causal flash attention (QBLK=128, 8 waves x 16 q-rows) ----------------
// grid: 1024 blocks; qt = 15-(bid>>6) (heavy-first LPT), bh = bid&63 (per-head XCD affinity).
// KV tile = 64, double-buffered LDS staging (32KB -> 4 blocks/CU).
// Swapped QK^T (mfma(K,Q)): full q-row's scores in-lane. P stays in REGISTERS:
// PV contracts over a permuted k-axis pi (baked into VT's column order by GEMM1),
// chosen so the A-frag is exactly concat(pk[0],pk[1]) / concat(pk[2],pk[3]).
__global__ __launch_bounds__(512, 2) void k_attn(
    const __bf16* __restrict__ qkv,  // [8192][3072]
    const __bf16* __restrict__ VT,   // [B*H][64][2048], pi-permuted columns per 64-tile
    __bf16* __restrict__ Y) {        // [8192][1024]
  __shared__ __bf16 kbuf[2][64 * 64];  // 8 KB per buf, row=kv pos, 128B rows, XOR-swizzled
  __shared__ __bf16 vbuf[2][64 * 64];  // 8 KB per buf, row=d,      128B rows, XOR-swizzled
  const int t = threadIdx.x, w = t >> 6, lane = t & 63;
  const int l15 = lane & 15, lg = lane >> 4;
  const int bid = blockIdx.x;
  const int qt = 15 - (bid >> 6);   // heavy q-blocks first
  const int bh = bid & 63;          // same head -> same XCD (round-robin dispatch)
  const int b = bh >> 4, h = bh & 15;
  const int q0 = qt * 128;
  const int nkv = 2 * qt + 2;
  const float SCL = 0.125f * 1.44269504f;  // scale * log2(e): softmax in exp2 domain

  const size_t qrow = (size_t)(b * 2048 + q0 + w * 16 + l15);
  const bf16x8 qf0 = *(const bf16x8*)(qkv + qrow * 3072 + h * 64 + lg * 8);
  const bf16x8 qf1 = *(const bf16x8*)(qkv + qrow * 3072 + h * 64 + 32 + lg * 8);

  const __bf16* kg = qkv + (size_t)(b * 2048) * 3072 + 1024 + h * 64;  // +kvpos*3072
  const __bf16* vg = VT + (size_t)bh * 64 * 2048;                      // +d*2048

  // 512 threads stage 8KB K + 8KB V per tile: 1 chunk of 16B each.
  const int srow = t >> 3, sslot = t & 7;          // row 0..63, slot 0..7
  const int sb = (sslot ^ (srow & 7)) << 4;        // pre-swizzled source byte
  auto stage = [&](int bi, int kvi) {
    gload_lds16((const char*)(kg + (size_t)(kvi * 64 + srow) * 3072) + sb,
                (char*)kbuf[bi] + w * 1024);
    gload_lds16((const char*)(vg + (size_t)srow * 2048 + kvi * 64) + sb,
                (char*)vbuf[bi] + w * 1024);
  };

  f32x4 o[4] = {};
  float mr = -1e30f, lr = 0.0f;   // running max (scaled domain) & sum for q-row w*16+l15

  stage(0, 0);
  asm volatile("s_waitcnt vmcnt(0)" ::: "memory");
  __syncthreads();

  for (int kv = 0; kv < nkv; ++kv) {
    if (kv + 1 < nkv) stage((kv + 1) & 1, kv + 1);  // prefetch next tile
    const char* kb = (const char*)kbuf[kv & 1];
    const char* vb = (const char*)vbuf[kv & 1];

    // QK^T swapped: s[nb] = K_tile * Q -> D[kv_local][q]; lane: q = l15, kv = nb*16+lg*4+r
    f32x4 s[4] = {};
    __builtin_amdgcn_s_setprio(1);
#pragma unroll
    for (int nb = 0; nb < 4; ++nb) {
      int row = nb * 16 + l15;
      int sw = (row & 7) << 4;
      bf16x8 k0 = *(const bf16x8*)(kb + row * 128 + ((lg * 16) ^ sw));
      bf16x8 k1 = *(const bf16x8*)(kb + row * 128 + ((64 + lg * 16) ^ sw));
      s[nb] = mfma_bf16(k0, qf0, s[nb]);
      s[nb] = mfma_bf16(k1, qf1, s[nb]);
    }
    __builtin_amdgcn_s_setprio(0);

    // causal mask: wave-uniform guard (tile reaches past this wave's first q-row)
    if (((kv + 1) << 6) > q0 + w * 16) {
      const int qg = q0 + w * 16 + l15;
#pragma unroll
      for (int nb = 0; nb < 4; ++nb)
#pragma unroll
        for (int r = 0; r < 4; ++r)
          if (kv * 64 + nb * 16 + lg * 4 + r > qg) s[nb][r] = -1e30f;
    }

    // row max: in-lane tree over 16 + xor16/32 (reduce over lg groups)
    float pm = -3e38f;
#pragma unroll
    for (int nb = 0; nb < 4; ++nb)
      pm = fmaxf(pm, fmaxf(fmaxf(s[nb][0], s[nb][1]), fmaxf(s[nb][2], s[nb][3])));
    pm = fmaxf(pm, __shfl_xor(pm, 16));
    pm = fmaxf(pm, __shfl_xor(pm, 32));
    pm *= SCL;

    if (!__all(pm <= mr + 8.0f)) {  // defer-max: rescale only when max grows
      float nm = fmaxf(mr, pm);
      float alpha = __builtin_amdgcn_exp2f(mr - nm);
      lr *= alpha;
      mr = nm;
#pragma unroll
      for (int r = 0; r < 4; ++r) {
        float aO = __shfl(alpha, lg * 4 + r);   // alpha of q-row lg*4+r
        o[0][r] *= aO; o[1][r] *= aO; o[2][r] *= aO; o[3][r] *= aO;
      }
    }

    // p = exp2(s*SCL - mr); sum in-lane + xor16/32
    float ps = 0.0f;
    bf16x4 pk[4];
#pragma unroll
    for (int nb = 0; nb < 4; ++nb) {
      f32x4 pe;
#pragma unroll
      for (int r = 0; r < 4; ++r)
        pe[r] = __builtin_amdgcn_exp2f(fmaf(s[nb][r], SCL, -mr));
      ps += (pe[0] + pe[1]) + (pe[2] + pe[3]);
      pk[nb][0] = (__bf16)pe[0]; pk[nb][1] = (__bf16)pe[1];
      pk[nb][2] = (__bf16)pe[2]; pk[nb][3] = (__bf16)pe[3];
    }
    ps += __shfl_xor(ps, 16);
    ps += __shfl_xor(ps, 32);
    lr += ps;

    // PV: A-frag comes straight from registers (pi-permuted k-axis, V columns match).
    const bf16x8 pf0 = __builtin_shufflevector(pk[0], pk[1], 0, 1, 2, 3, 4, 5, 6, 7);
    const bf16x8 pf1 = __builtin_shufflevector(pk[2], pk[3], 0, 1, 2, 3, 4, 5, 6, 7);
    __builtin_amdgcn_s_setprio(1);
#pragma unroll
    for (int nb = 0; nb < 4; ++nb) {
      int row = nb * 16 + l15;
      int sw = (row & 7) << 4;
      bf16x8 v0 = *(const bf16x8*)(vb + row * 128 + ((lg * 16) ^ sw));
      bf16x8 v1 = *(const bf16x8*)(vb + row * 128 + ((64 + lg * 16) ^ sw));
      o[nb] = mfma_bf16(pf0, v0, o[nb]);
      o[nb] = mfma_bf16(pf1, v1, o[nb]);
    }
    __builtin_amdgcn_s_setprio(0);
    asm volatile("s_waitcnt vmcnt(0)" ::: "memory");  // next tile fully staged
    __syncthreads();                                  // everyone done with cur buffers
  }

  float lO[4];
#pragma unroll
  for (int r = 0; r < 4; ++r) lO[r] = __shfl(lr, lg * 4 + r);
#pragma unroll
  for (int nb = 0; nb < 4; ++nb)
#pragma unroll
    for (int r = 0; r < 4; ++r) {
      float v = o[nb][r] / lO[r];
      size_t row = (size_t)(b * 2048 + q0 + w * 16 + lg * 4 + r);
      Y[row * 1024 + h * 64 + nb * 16 + l15] = (__bf16)v;
    }
}

extern "C" void kernel_launch(void* const* d_in, const int* in_sizes, int n_in,
                              void* d_out, int out_size, void* d_ws, size_t ws_size,
                              hipStream_t stream) {
  const float* x      = (const float*)d_in[0];
  const float* w_qkv  = (const float*)d_in[1];
  const float* b_qkv  = (const float*)d_in[2];
  const float* w_proj = (const float*)d_in[3];
  const float* b_proj = (const float*)d_in[4];
  float* out = (float*)d_out;

  char* ws = (char*)d_ws;
  const size_t MB = 1024 * 1024;
  __bf16* xb     = (__bf16*)(ws);            // 16 MiB  [8192][1024]
  __bf16* wqkvT  = (__bf16*)(ws + 16 * MB);  // 6 MiB   [3072][1024]
  __bf16* wprojT = (__bf16*)(ws + 22 * MB);  // 2 MiB   [1024][1024]
  __bf16* qkv    = (__bf16*)(ws + 24 * MB);  // 48 MiB  [8192][3072] (V section unused)
  __bf16* VT     = (__bf16*)(ws + 72 * MB);  // 16 MiB  [64][64][2048] (pi-permuted)
  __bf16* Y      = (__bf16*)(ws + 88 * MB);  // 16 MiB  [8192][1024]  (ends 104 MiB)

  k_cast_bf16<<<8192, 256, 0, stream>>>(x, xb, 8192 * 1024 / 4);
  k_transpose_cast<<<dim3(48, 16), 256, 0, stream>>>(w_qkv, wqkvT, 1024, 3072);
  k_transpose_cast<<<dim3(16, 16), 256, 0, stream>>>(w_proj, wprojT, 1024, 1024);
  k_gemm_bt<0><<<dim3(64 * 24), 256, 0, stream>>>(xb, wqkvT, b_qkv, qkv, VT, 8192, 3072, 1024, 24);
  k_attn<<<dim3(1024), 512, 0, stream>>>(qkv, VT, Y);
  k_gemm_bt<1><<<dim3(64 * 8), 256, 0, stream>>>(Y, wprojT, b_proj, out, nullptr, 8192, 1024, 1024, 8);
}

// Round 9
// 165.359 us; speedup vs baseline: 1.2846x; 1.0355x over previous
//
#include <hip/hip_runtime.h>
#include <cstdint>
#include <cstddef>

// B=4, S=2048, D=1024, H=16, HD=64 ; BS=8192 rows; qkv N=3072
typedef float  f32x4  __attribute__((ext_vector_type(4)));
typedef __bf16 bf16x8 __attribute__((ext_vector_type(8)));
typedef __bf16 bf16x4 __attribute__((ext_vector_type(4)));

#define DEVI static __device__ __forceinline__

DEVI f32x4 mfma_bf16(bf16x8 a, bf16x8 b, f32x4 c) {
  return __builtin_amdgcn_mfma_f32_16x16x32_bf16(a, b, c, 0, 0, 0);
}

DEVI void gload_lds16(const void* g, void* l) {
  __builtin_amdgcn_global_load_lds(
      (const __attribute__((address_space(1))) void*)g,
      (__attribute__((address_space(3))) void*)l, 16, 0, 0);
}

// ---------------- fused prep: cast x->bf16 ; transpose-cast w_qkv, w_proj ----------------
// blocks [0,8192): cast 1024 elems each; [8192,8960): w_qkv T; [8960,9216): w_proj T.
__global__ __launch_bounds__(256) void k_prep(
    const float* __restrict__ x, __bf16* __restrict__ xb,
    const float* __restrict__ w_qkv, __bf16* __restrict__ wqkvT,
    const float* __restrict__ w_proj, __bf16* __restrict__ wprojT) {
  __shared__ __bf16 tile[64][65];
  const int idx = blockIdx.x;
  if (idx < 8192) {
    int i = idx * 256 + threadIdx.x;
    float4 v = reinterpret_cast<const float4*>(x)[i];
    bf16x4 r;
    r.x = (__bf16)v.x; r.y = (__bf16)v.y; r.z = (__bf16)v.z; r.w = (__bf16)v.w;
    reinterpret_cast<bf16x4*>(xb)[i] = r;
    return;
  }
  const float* src; __bf16* dst; int R, C, bx, by;
  if (idx < 8960) {
    int id2 = idx - 8192; bx = id2 % 48; by = id2 / 48;
    src = w_qkv; dst = wqkvT; R = 1024; C = 3072;
  } else {
    int id2 = idx - 8960; bx = id2 % 16; by = id2 / 16;
    src = w_proj; dst = wprojT; R = 1024; C = 1024;
  }
  const int tx = threadIdx.x & 63, ty = threadIdx.x >> 6;
  const int r0 = by * 64, c0 = bx * 64;
#pragma unroll
  for (int i = 0; i < 16; ++i) {
    int r = ty * 16 + i;
    tile[r][tx] = (__bf16)src[(size_t)(r0 + r) * C + c0 + tx];
  }
  __syncthreads();
#pragma unroll
  for (int i = 0; i < 16; ++i) {
    int c = ty * 16 + i;
    dst[(size_t)(c0 + c) * R + r0 + tx] = tile[tx][c];
  }
}

// ---------------- bf16 GEMM: C[M][N] = A[M][K] * Bt[N][K]^T + bias ----------------
// 128x128 tile, BK=64, 4 waves (2x2), global_load_lds staging with both-sides XOR swizzle.
// MODE 0: bf16 out; V-section blocks (n0>=2048, VT!=null) write transposed into
// VT[bh][d][s] with packed bf16x4 stores AND a per-64-tile nibble permutation of s
// (pi^-1) so attention's PV can consume P directly from registers (see k_attn).
// MODE 1: f32 out.
template <int MODE>
__global__ __launch_bounds__(256, 2) void k_gemm_bt(
    const __bf16* __restrict__ A, const __bf16* __restrict__ Bt,
    const float* __restrict__ bias, void* __restrict__ Cv,
    __bf16* __restrict__ VT,
    int M, int N, int K, int nbx) {
  __shared__ __bf16 As[128 * 64];
  __shared__ __bf16 Bs[128 * 64];
  const int t = threadIdx.x;
  const int w = t >> 6, lane = t & 63;
  const int l15 = lane & 15, lg = lane >> 4;
  const int m0 = (blockIdx.x / nbx) * 128;
  const int n0 = (blockIdx.x % nbx) * 128;
  const int wr = w >> 1, wc = w & 1;
  const int lrow = lane >> 3, lslot = lane & 7;

  f32x4 acc[4][4] = {};

  const int nK = K >> 6;
  for (int kt = 0; kt < nK; ++kt) {
    const __bf16* Ab = A + (size_t)m0 * K + kt * 64;
    const __bf16* Bb = Bt + (size_t)n0 * K + kt * 64;
#pragma unroll
    for (int c = 0; c < 4; ++c) {
      int seg = w * 4 + c;            // 16 segments of 1KB per tile
      int row = seg * 8 + lrow;       // 0..127
      int cb = (lslot ^ (row & 7)) << 4;  // pre-swizzled global source byte
      gload_lds16((const char*)(Ab + (size_t)row * K) + cb, (char*)As + seg * 1024);
      gload_lds16((const char*)(Bb + (size_t)row * K) + cb, (char*)Bs + seg * 1024);
    }
    __syncthreads();
#pragma unroll
    for (int ks = 0; ks < 2; ++ks) {
      bf16x8 af[4], bfr[4];
      const int cb = ks * 64 + (lg << 4);
#pragma unroll
      for (int m = 0; m < 4; ++m) {
        int row = wr * 64 + m * 16 + l15;
        af[m] = *(const bf16x8*)((const char*)As + row * 128 + (cb ^ ((row & 7) << 4)));
      }
#pragma unroll
      for (int n = 0; n < 4; ++n) {
        int row = wc * 64 + n * 16 + l15;
        bfr[n] = *(const bf16x8*)((const char*)Bs + row * 128 + (cb ^ ((row & 7) << 4)));
      }
#pragma unroll
      for (int m = 0; m < 4; ++m)
#pragma unroll
        for (int n = 0; n < 4; ++n)
          acc[m][n] = mfma_bf16(af[m], bfr[n], acc[m][n]);
    }
    __syncthreads();
  }

  const bool vsec = (MODE == 0) && (VT != nullptr) && (n0 >= 2048);
#pragma unroll
  for (int n = 0; n < 4; ++n) {
    const int gcol = n0 + wc * 64 + n * 16 + l15;
    const float bv = bias ? bias[gcol] : 0.0f;
#pragma unroll
    for (int m = 0; m < 4; ++m) {
      const int grow = m0 + wr * 64 + m * 16 + (lg << 2);
      if (vsec) {
        // V section: write VT[(b*16+h)*64 + d][s'] where s' applies the per-64-tile
        // nibble permutation pi^-1: m<4:2m ; 4..7:2m-7 ; 8..11:2m-8 ; 12..15:2m-15.
        const int hd = gcol - 2048;           // h*64 + d
        const int b = grow >> 11, s0v = grow & 2047;
        const int nib = (s0v >> 2) & 15;
        const int nib2 = (nib < 4) ? 2 * nib : (nib < 8) ? 2 * nib - 7
                        : (nib < 12) ? 2 * nib - 8 : 2 * nib - 15;
        const int sp = (s0v & ~63) | (nib2 << 2);
        bf16x4 pkv;
#pragma unroll
        for (int r = 0; r < 4; ++r) pkv[r] = (__bf16)(acc[m][n][r] + bv);
        *(bf16x4*)(VT + ((size_t)(b * 16) * 64 + hd) * 2048 + sp) = pkv;
      } else {
#pragma unroll
        for (int r = 0; r < 4; ++r) {
          float v = acc[m][n][r] + bv;
          if (MODE == 0)
            ((__bf16*)Cv)[(size_t)(grow + r) * N + gcol] = (__bf16)v;
          else
            ((float*)Cv)[(size_t)(grow + r) * N + gcol] = v;
        }
      }
    }
  }
}

// ---------------- causal flash attention (QBLK=128, 8 waves x 16 q-rows) ----------------
// grid: 1024 blocks; g=bid>>6 maps to qt via a CU-balanced schedule: the 4 blocks that
// land on one CU (g offsets {0,4,8,12}, round-robin dispatch period 256) sum to equal
// work (34 units) for every CU. bh = bid&63 keeps per-head XCD affinity (XCD=bh&7).
// KV tile = 64, double-buffered LDS staging (32KB -> 4 blocks/CU).
// Swapped QK^T (mfma(K,Q)): full q-row's scores in-lane. P stays in REGISTERS:
// PV contracts over a permuted k-axis pi (baked into VT's column order by GEMM1).
__global__ __launch_bounds__(512, 2) void k_attn(
    const __bf16* __restrict__ qkv,  // [8192][3072]
    const __bf16* __restrict__ VT,   // [B*H][64][2048], pi-permuted columns per 64-tile
    __bf16* __restrict__ Y) {        // [8192][1024]
  __shared__ __bf16 kbuf[2][64 * 64];  // 8 KB per buf, row=kv pos, 128B rows, XOR-swizzled
  __shared__ __bf16 vbuf[2][64 * 64];  // 8 KB per buf, row=d,      128B rows, XOR-swizzled
  const int t = threadIdx.x, w = t >> 6, lane = t & 63;
  const int l15 = lane & 15, lg = lane >> 4;
  const int bid = blockIdx.x;
  const int g = bid >> 6;
  const int qt = (g < 4) ? 15 - g : (g < 8) ? g - 4 : (g < 12) ? 19 - g : g - 8;
  const int bh = bid & 63;          // same head -> same XCD (round-robin dispatch)
  const int b = bh >> 4, h = bh & 15;
  const int q0 = qt * 128;
  const int nkv = 2 * qt + 2;
  const float SCL = 0.125f * 1.44269504f;  // scale * log2(e): softmax in exp2 domain

  const size_t qrow = (size_t)(b * 2048 + q0 + w * 16 + l15);
  const bf16x8 qf0 = *(const bf16x8*)(qkv + qrow * 3072 + h * 64 + lg * 8);
  const bf16x8 qf1 = *(const bf16x8*)(qkv + qrow * 3072 + h * 64 + 32 + lg * 8);

  const __bf16* kg = qkv + (size_t)(b * 2048) * 3072 + 1024 + h * 64;  // +kvpos*3072
  const __bf16* vg = VT + (size_t)bh * 64 * 2048;                      // +d*2048

  // 512 threads stage 8KB K + 8KB V per tile: 1 chunk of 16B each.
  const int srow = t >> 3, sslot = t & 7;          // row 0..63, slot 0..7
  const int sb = (sslot ^ (srow & 7)) << 4;        // pre-swizzled source byte
  auto stage = [&](int bi, int kvi) {
    gload_lds16((const char*)(kg + (size_t)(kvi * 64 + srow) * 3072) + sb,
                (char*)kbuf[bi] + w * 1024);
    gload_lds16((const char*)(vg + (size_t)srow * 2048 + kvi * 64) + sb,
                (char*)vbuf[bi] + w * 1024);
  };

  f32x4 o[4] = {};
  float mr = -1e30f, lr = 0.0f;   // running max (scaled domain) & sum for q-row w*16+l15

  stage(0, 0);
  asm volatile("s_waitcnt vmcnt(0)" ::: "memory");
  __syncthreads();

  for (int kv = 0; kv < nkv; ++kv) {
    if (kv + 1 < nkv) stage((kv + 1) & 1, kv + 1);  // prefetch next tile
    const char* kb = (const char*)kbuf[kv & 1];
    const char* vb = (const char*)vbuf[kv & 1];

    // QK^T swapped: s[nb] = K_tile * Q -> D[kv_local][q]; lane: q = l15, kv = nb*16+lg*4+r
    f32x4 s[4] = {};
    __builtin_amdgcn_s_setprio(1);
#pragma unroll
    for (int nb = 0; nb < 4; ++nb) {
      int row = nb * 16 + l15;
      int sw = (row & 7) << 4;
      bf16x8 k0 = *(const bf16x8*)(kb + row * 128 + ((lg * 16) ^ sw));
      bf16x8 k1 = *(const bf16x8*)(kb + row * 128 + ((64 + lg * 16) ^ sw));
      s[nb] = mfma_bf16(k0, qf0, s[nb]);
      s[nb] = mfma_bf16(k1, qf1, s[nb]);
    }
    __builtin_amdgcn_s_setprio(0);

    // causal mask: wave-uniform guard (tile reaches past this wave's first q-row)
    if (((kv + 1) << 6) > q0 + w * 16) {
      const int qg = q0 + w * 16 + l15;
#pragma unroll
      for (int nb = 0; nb < 4; ++nb)
#pragma unroll
        for (int r = 0; r < 4; ++r)
          if (kv * 64 + nb * 16 + lg * 4 + r > qg) s[nb][r] = -1e30f;
    }

    // row max: max3-friendly tree (8 ops) + xor16/32 cross-group reduce
    float a0 = fmaxf(fmaxf(s[0][0], s[0][1]), s[0][2]);
    float a1 = fmaxf(fmaxf(s[0][3], s[1][0]), s[1][1]);
    float a2 = fmaxf(fmaxf(s[1][2], s[1][3]), s[2][0]);
    float a3 = fmaxf(fmaxf(s[2][1], s[2][2]), s[2][3]);
    float a4 = fmaxf(fmaxf(s[3][0], s[3][1]), s[3][2]);
    float pm = fmaxf(fmaxf(fmaxf(a0, a1), a2), fmaxf(fmaxf(a3, a4), s[3][3]));
    pm = fmaxf(pm, __shfl_xor(pm, 16));
    pm = fmaxf(pm, __shfl_xor(pm, 32));
    pm *= SCL;

    if (!__all(pm <= mr + 8.0f)) {  // defer-max: rescale only when max grows
      float nm = fmaxf(mr, pm);
      float alpha = __builtin_amdgcn_exp2f(mr - nm);
      lr *= alpha;
      mr = nm;
#pragma unroll
      for (int r = 0; r < 4; ++r) {
        float aO = __shfl(alpha, lg * 4 + r);   // alpha of q-row lg*4+r
        o[0][r] *= aO; o[1][r] *= aO; o[2][r] *= aO; o[3][r] *= aO;
      }
    }

    // p = exp2(s*SCL - mr); sum in-lane + xor16/32
    float ps = 0.0f;
    bf16x4 pk[4];
#pragma unroll
    for (int nb = 0; nb < 4; ++nb) {
      f32x4 pe;
#pragma unroll
      for (int r = 0; r < 4; ++r)
        pe[r] = __builtin_amdgcn_exp2f(fmaf(s[nb][r], SCL, -mr));
      ps += (pe[0] + pe[1]) + (pe[2] + pe[3]);
      pk[nb][0] = (__bf16)pe[0]; pk[nb][1] = (__bf16)pe[1];
      pk[nb][2] = (__bf16)pe[2]; pk[nb][3] = (__bf16)pe[3];
    }
    ps += __shfl_xor(ps, 16);
    ps += __shfl_xor(ps, 32);
    lr += ps;

    // PV: A-frag comes straight from registers (pi-permuted k-axis, V columns match).
    const bf16x8 pf0 = __builtin_shufflevector(pk[0], pk[1], 0, 1, 2, 3, 4, 5, 6, 7);
    const bf16x8 pf1 = __builtin_shufflevector(pk[2], pk[3], 0, 1, 2, 3, 4, 5, 6, 7);
    __builtin_amdgcn_s_setprio(1);
#pragma unroll
    for (int nb = 0; nb < 4; ++nb) {
      int row = nb * 16 + l15;
      int sw = (row & 7) << 4;
      bf16x8 v0 = *(const bf16x8*)(vb + row * 128 + ((lg * 16) ^ sw));
      bf16x8 v1 = *(const bf16x8*)(vb + row * 128 + ((64 + lg * 16) ^ sw));
      o[nb] = mfma_bf16(pf0, v0, o[nb]);
      o[nb] = mfma_bf16(pf1, v1, o[nb]);
    }
    __builtin_amdgcn_s_setprio(0);
    asm volatile("s_waitcnt vmcnt(0)" ::: "memory");  // next tile fully staged
    __syncthreads();                                  // everyone done with cur buffers
  }

  float lO[4];
#pragma unroll
  for (int r = 0; r < 4; ++r) lO[r] = __shfl(lr, lg * 4 + r);
#pragma unroll
  for (int nb = 0; nb < 4; ++nb)
#pragma unroll
    for (int r = 0; r < 4; ++r) {
      float v = o[nb][r] / lO[r];
      size_t row = (size_t)(b * 2048 + q0 + w * 16 + lg * 4 + r);
      Y[row * 1024 + h * 64 + nb * 16 + l15] = (__bf16)v;
    }
}

extern "C" void kernel_launch(void* const* d_in, const int* in_sizes, int n_in,
                              void* d_out, int out_size, void* d_ws, size_t ws_size,
                              hipStream_t stream) {
  const float* x      = (const float*)d_in[0];
  const float* w_qkv  = (const float*)d_in[1];
  const float* b_qkv  = (const float*)d_in[2];
  const float* w_proj = (const float*)d_in[3];
  const float* b_proj = (const float*)d_in[4];
  float* out = (float*)d_out;

  char* ws = (char*)d_ws;
  const size_t MB = 1024 * 1024;
  __bf16* xb     = (__bf16*)(ws);            // 16 MiB  [8192][1024]
  __bf16* wqkvT  = (__bf16*)(ws + 16 * MB);  // 6 MiB   [3072][1024]
  __bf16* wprojT = (__bf16*)(ws + 22 * MB);  // 2 MiB   [1024][1024]
  __bf16* qkv    = (__bf16*)(ws + 24 * MB);  // 48 MiB  [8192][3072] (V section unused)
  __bf16* VT     = (__bf16*)(ws + 72 * MB);  // 16 MiB  [64][64][2048] (pi-permuted)
  __bf16* Y      = (__bf16*)(ws + 88 * MB);  // 16 MiB  [8192][1024]  (ends 104 MiB)

  k_prep<<<dim3(9216), 256, 0, stream>>>(x, xb, w_qkv, wqkvT, w_proj, wprojT);
  k_gemm_bt<0><<<dim3(64 * 24), 256, 0, stream>>>(xb, wqkvT, b_qkv, qkv, VT, 8192, 3072, 1024, 24);
  k_attn<<<dim3(1024), 512, 0, stream>>>(qkv, VT, Y);
  k_gemm_bt<1><<<dim3(64 * 8), 256, 0, stream>>>(Y, wprojT, b_proj, out, nullptr, 8192, 1024, 1024, 8);
}